// Round 13
// baseline (974.536 us; speedup 1.0000x reference)
//
#include <hip/hip_runtime.h>
#include <math.h>

// SchNet forward on MI355X.
// R1: edge filter W(d)*C(d) tabulated (4096-pt lerp) -> removed 94% of FLOPs.
// R2: CSR sort -> gather-only aggregation, no atomics.
// R3: x,T bf16. R6: node GEMMs -> MFMA bf16, packed B-fragments, swizzled LDS.
// R7: k_agg unroll x4; MFMA k_out + segmented atomics; bf16 k_table.
// R11: 3-phase parallel scan; k_mfma1+k_out fused into k_fused (3 GEMM
//      passes through one LDS tile).
// R13: agg stored as PRE-SWIZZLED bf16 by k_agg (k_fused staging = plain
//      uint4 copy, no f2bf/no swizzle math; agg bytes halved; bit-identical
//      numerics since the bf16 convert just moved producer-side);
//      paired table Tp[j]=(T[j],T[j+1]) -> one uint2 load per edge per lane
//      instead of two 4B loads (k_pair builds it, 2MB).

constexpr int Nn  = 50000;
constexpr int Ee  = 800000;
constexpr int Gg  = 512;
constexpr int Hh  = 128;
constexpr int NGg = 50;
constexpr int NIi = 6;
constexpr int TS  = 4096;           // table size
constexpr int NB  = (Nn + 255) / 256;   // 196 scan blocks
constexpr float DMAXv = 8.6603f;    // > 5*sqrt(3) = 8.660254 (pos in [0,5)^3)

typedef short bf16x8 __attribute__((ext_vector_type(8)));
typedef float f32x4  __attribute__((ext_vector_type(4)));

__device__ __forceinline__ float ssp(float v) {
    return log1pf(__expf(-fabsf(v))) + fmaxf(v, 0.0f) - 0.69314718056f;
}
__device__ __forceinline__ unsigned short f2bf(float f) {   // RNE
    unsigned int u = __float_as_uint(f);
    u += 0x7fffu + ((u >> 16) & 1u);
    return (unsigned short)(u >> 16);
}
__device__ __forceinline__ float bf2f(unsigned int h) {     // h: low 16 bits
    return __uint_as_float(h << 16);
}

// ---------------- h = emb[z]  ----------------
__global__ void k_embed(const float* __restrict__ emb, const int* __restrict__ z,
                        float* __restrict__ h) {
    int tid = blockIdx.x * 256 + threadIdx.x;   // N*128 threads exactly
    int n = tid >> 7, f = tid & 127;
    h[tid] = emb[z[n] * Hh + f];
}

// ---------------- CSR build ----------------
__global__ void k_hist(const int* __restrict__ ei, int* __restrict__ counts) {
    int e = blockIdx.x * 256 + threadIdx.x;
    if (e >= Ee) return;
    atomicAdd(&counts[ei[e]], 1);
}

// 3-phase parallel exclusive scan over counts[Nn]
__global__ __launch_bounds__(256) void k_scanA(const int* __restrict__ counts,
                                               int* __restrict__ incl,
                                               int* __restrict__ bsum) {
    int t = blockIdx.x * 256 + threadIdx.x;
    int lane = threadIdx.x & 63, wv = threadIdx.x >> 6;
    int c = (t < Nn) ? counts[t] : 0;
    int v = c;
    #pragma unroll
    for (int off = 1; off < 64; off <<= 1) {
        int u = __shfl_up(v, off);
        if (lane >= off) v += u;
    }
    __shared__ int ws[4];
    if (lane == 63) ws[wv] = v;
    __syncthreads();
    if (threadIdx.x == 0) {
        int s = 0;
        #pragma unroll
        for (int i = 0; i < 4; ++i) { int x = ws[i]; ws[i] = s; s += x; }
        bsum[blockIdx.x] = s;
    }
    __syncthreads();
    v += ws[wv];
    if (t < Nn) incl[t] = v;            // block-inclusive prefix
}

__global__ __launch_bounds__(256) void k_scanB(int* __restrict__ bsum) {
    __shared__ int s[256];
    int t = threadIdx.x;
    int v = (t < NB) ? bsum[t] : 0;
    s[t] = v;
    __syncthreads();
    for (int off = 1; off < 256; off <<= 1) {
        int u = (t >= off) ? s[t - off] : 0;
        __syncthreads();
        s[t] += u;
        __syncthreads();
    }
    if (t < NB) bsum[t] = s[t] - v;     // exclusive block base
}

__global__ __launch_bounds__(256) void k_scanC(const int* __restrict__ counts,
                                               const int* __restrict__ incl,
                                               const int* __restrict__ bsum,
                                               int* __restrict__ offsets,
                                               int* __restrict__ cursor) {
    int t = blockIdx.x * 256 + threadIdx.x;
    if (t >= Nn) return;
    int off = bsum[blockIdx.x] + incl[t] - counts[t];
    offsets[t] = off;
    cursor[t]  = off;
    if (t == Nn - 1) offsets[Nn] = off + counts[t];
}

__global__ void k_scatter(const int* __restrict__ ei, const float* __restrict__ pos,
                          int* __restrict__ cursor, int2* __restrict__ payload,
                          float inv_step) {
    int e = blockIdx.x * 256 + threadIdx.x;
    if (e >= Ee) return;
    int r = ei[e], c = ei[Ee + e];
    float dx = pos[3 * r    ] - pos[3 * c    ];
    float dy = pos[3 * r + 1] - pos[3 * c + 1];
    float dz = pos[3 * r + 2] - pos[3 * c + 2];
    float d = sqrtf(dx * dx + dy * dy + dz * dz + 1e-12f);
    float u = d * inv_step;
    if (u > (float)(TS - 1) - 5e-4f) u = (float)(TS - 1) - 5e-4f;
    int p = atomicAdd(&cursor[r], 1);
    payload[p] = make_int2(c, __float_as_int(u));
}

// ---------------- weight packer: fp32 -> bf16 MFMA B-fragments ----------------
// 18 matrices [128][128] + ow1 [128][64].
// Frag: Wp[((nt*4+kk)*64 + l)*8 + e] = bf16(W[kk*32+(l>>4)*8+e][nt*16+(l&15)])
__global__ void k_pack(const float* __restrict__ lin1, const float* __restrict__ lin2,
                       const float* __restrict__ lin3, const float* __restrict__ ow1,
                       short* __restrict__ Wp) {
    int o = blockIdx.x * 256 + threadIdx.x;        // 18*16384 + 8192 total
    if (o < 18 * 16384) {
        int m = o >> 14, r = o & 16383;
        int k = (r >> 7) & 127, c = r & 127;
        int i = m / 3, which = m % 3;
        const float* src = which == 0 ? lin1 : (which == 1 ? lin2 : lin3);
        float v = src[(size_t)i * 16384 + k * 128 + c];
        int nt = c >> 4, lc = c & 15, kk = k >> 5, kg = (k >> 3) & 3, e = k & 7;
        int l = kg * 16 + lc;
        Wp[(size_t)m * 16384 + ((nt * 4 + kk) * 64 + l) * 8 + e] = (short)f2bf(v);
    } else {
        int r = o - 18 * 16384;                    // 0..8191
        int k = r >> 6, c = r & 63;
        float v = ow1[k * 64 + c];
        int nt = c >> 4, lc = c & 15, kk = k >> 5, kg = (k >> 3) & 3, e = k & 7;
        int l = kg * 16 + lc;
        Wp[(size_t)18 * 16384 + ((nt * 4 + kk) * 64 + l) * 8 + e] = (short)f2bf(v);
    }
}

// ---------------- filter table (bf16 out): 512 blocks x 8 j ----------------
__global__ __launch_bounds__(256) void k_table(
        const float* __restrict__ w1, const float* __restrict__ b1,
        const float* __restrict__ w2, const float* __restrict__ b2,
        unsigned short* __restrict__ T, float step) {
    __shared__ unsigned int w2p[64 * 128];   // 32 KB: (k2,f) -> bf16 pair
    __shared__ unsigned int w1p[25 * 128];   // 12.5 KB
    __shared__ float rbf_s[2][NGg];
    __shared__ float tb[2][128];
    int tid = threadIdx.x;
    for (int i = tid; i < 64 * 128; i += 256) {
        int k2 = i >> 7, f = i & 127;
        unsigned int lo = f2bf(w2[(2 * k2) * 128 + f]);
        unsigned int hi = f2bf(w2[(2 * k2 + 1) * 128 + f]);
        w2p[i] = lo | (hi << 16);
    }
    for (int i = tid; i < 25 * 128; i += 256) {
        int k2 = i >> 7, f = i & 127;
        unsigned int lo = f2bf(w1[(2 * k2) * 128 + f]);
        unsigned int hi = f2bf(w1[(2 * k2 + 1) * 128 + f]);
        w1p[i] = lo | (hi << 16);
    }
    int jj = tid >> 7, f = tid & 127;
    float bb1 = b1[f], bb2 = b2[f];
    for (int p = 0; p < 4; ++p) {
        int j = blockIdx.x * 8 + p * 2 + jj;
        float dj = j * step;
        __syncthreads();
        if (f < NGg) {
            float u = dj - f * (10.0f / 49.0f);
            rbf_s[jj][f] = expf(-12.00500f * u * u);   // -0.5/(10/49)^2
        }
        __syncthreads();
        float u = bb1;
        for (int k2 = 0; k2 < 25; ++k2) {
            unsigned int wv = w1p[k2 * 128 + f];
            u = fmaf(rbf_s[jj][2 * k2    ], bf2f(wv & 0xffffu), u);
            u = fmaf(rbf_s[jj][2 * k2 + 1], bf2f(wv >> 16), u);
        }
        tb[jj][f] = ssp(u);
        __syncthreads();
        float w = bb2;
        for (int k2 = 0; k2 < 64; ++k2) {
            unsigned int wv = w2p[k2 * 128 + f];
            w = fmaf(tb[jj][2 * k2    ], bf2f(wv & 0xffffu), w);
            w = fmaf(tb[jj][2 * k2 + 1], bf2f(wv >> 16), w);
        }
        float C = 0.5f * (cosf(dj * 0.31415926535f) + 1.0f);  // pi/10
        T[j * 128 + f] = f2bf(w * C);
    }
}

// ---------------- paired table: Tp[j][lane] = (rowj, rowj+1) uints -----------
__global__ __launch_bounds__(256) void k_pair(const unsigned int* __restrict__ Tu,
                                              uint2* __restrict__ Tp) {
    int i = blockIdx.x * 256 + threadIdx.x;     // 0 .. TS*64-1
    int j = i >> 6, l = i & 63;
    unsigned int a = Tu[j * 64 + l];
    unsigned int b = (j < TS - 1) ? Tu[(j + 1) * 64 + l] : a;
    Tp[i] = make_uint2(a, b);
}

// ---------------- MFMA: x(bf16) = h @ lin1 (first iteration only) -------------
__global__ __launch_bounds__(256) void k_mfma1(
        const float* __restrict__ in, const short* __restrict__ Wp,
        unsigned short* __restrict__ out, int nrows) {
    __shared__ short As[64 * 128];
    int tid = threadIdx.x;
    int base = blockIdx.x * 64;
    const float4* in4 = (const float4*)(in + (size_t)base * 128);
    int lim4 = (nrows - base) * 32;
    for (int i = tid; i < 2048; i += 256) {
        float4 v = make_float4(0.f, 0.f, 0.f, 0.f);
        if (i < lim4) v = in4[i];
        ushort4 o; o.x = f2bf(v.x); o.y = f2bf(v.y); o.z = f2bf(v.z); o.w = f2bf(v.w);
        int row = i >> 5, colg = i & 31;
        int byte = (row * 256 + colg * 8) ^ ((row & 7) << 4);
        *(ushort4*)((char*)As + byte) = o;
    }
    __syncthreads();

    int w = tid >> 6, lane = tid & 63;
    int arow = w * 16 + (lane & 15);
    bf16x8 a[4];
    #pragma unroll
    for (int kk = 0; kk < 4; ++kk) {
        int byte = (arow * 256 + kk * 64 + (lane >> 4) * 16) ^ ((arow & 7) << 4);
        a[kk] = *(const bf16x8*)((const char*)As + byte);
    }
    f32x4 acc[8];
    f32x4 zero = {0.f, 0.f, 0.f, 0.f};
    #pragma unroll
    for (int nt = 0; nt < 8; ++nt) acc[nt] = zero;
    const bf16x8* Wp8 = (const bf16x8*)Wp;
    #pragma unroll
    for (int nt = 0; nt < 8; ++nt)
        #pragma unroll
        for (int kk = 0; kk < 4; ++kk)
            acc[nt] = __builtin_amdgcn_mfma_f32_16x16x32_bf16(
                a[kk], Wp8[(nt * 4 + kk) * 64 + lane], acc[nt], 0, 0, 0);
    #pragma unroll
    for (int nt = 0; nt < 8; ++nt) {
        int col = nt * 16 + (lane & 15);
        #pragma unroll
        for (int r = 0; r < 4; ++r) {
            int row = base + w * 16 + (lane >> 4) * 4 + r;
            if (row < nrows) out[(size_t)row * 128 + col] = f2bf(acc[nt][r]);
        }
    }
}

// ---------------- fused interaction tail -------------------------------------
// Stages PRE-SWIZZLED bf16 agg (plain uint4 copy). Then:
// h_new = h + ssp(agg@W2+b2)@W3 + b3 ; then EITHER x_next = h_new@Wnext (bf16
// to xb) OR (last iter) readout: ssp(h_new@OW1+ob1)*ow2 row-sum -> energy.
__global__ __launch_bounds__(256) void k_fused(
        const unsigned int* __restrict__ aggp, const short* __restrict__ W2p,
        const float* __restrict__ b2, const short* __restrict__ W3p,
        const float* __restrict__ b3, float* __restrict__ h,
        const short* __restrict__ Wnext, unsigned short* __restrict__ xb,
        const short* __restrict__ OW1p, const float* __restrict__ ob1,
        const float* __restrict__ ow2, const float* __restrict__ ob2,
        const int* __restrict__ batch, float* __restrict__ energy, int nrows) {
    __shared__ short As[64 * 128];
    __shared__ float rowsum[64];
    int tid = threadIdx.x;
    int base = blockIdx.x * 64;
    // staging: aggp is already bf16 in the swizzled chunk order -> linear copy
    {
        const uint4* gp = (const uint4*)aggp + (size_t)blockIdx.x * 1024;
        uint4* As4 = (uint4*)As;
        #pragma unroll
        for (int i = 0; i < 4; ++i) As4[i * 256 + tid] = gp[i * 256 + tid];
    }
    __syncthreads();

    int w = tid >> 6, lane = tid & 63;
    int arow = w * 16 + (lane & 15);
    f32x4 zero = {0.f, 0.f, 0.f, 0.f};
    bf16x8 a[4];
    #pragma unroll
    for (int kk = 0; kk < 4; ++kk) {
        int byte = (arow * 256 + kk * 64 + (lane >> 4) * 16) ^ ((arow & 7) << 4);
        a[kk] = *(const bf16x8*)((const char*)As + byte);
    }
    f32x4 acc[8];
    #pragma unroll
    for (int nt = 0; nt < 8; ++nt) acc[nt] = zero;
    const bf16x8* W2p8 = (const bf16x8*)W2p;
    #pragma unroll
    for (int nt = 0; nt < 8; ++nt)
        #pragma unroll
        for (int kk = 0; kk < 4; ++kk)
            acc[nt] = __builtin_amdgcn_mfma_f32_16x16x32_bf16(
                a[kk], W2p8[(nt * 4 + kk) * 64 + lane], acc[nt], 0, 0, 0);

    // t = ssp(acc + b2) -> back into own 16-row stripe of the LDS tile
    #pragma unroll
    for (int nt = 0; nt < 8; ++nt) {
        int col = nt * 16 + (lane & 15);
        float bv = b2[col];
        #pragma unroll
        for (int r = 0; r < 4; ++r) {
            int row = w * 16 + (lane >> 4) * 4 + r;
            int byte = (row * 256 + col * 2) ^ ((row & 7) << 4);
            *(unsigned short*)((char*)As + byte) = f2bf(ssp(acc[nt][r] + bv));
        }
    }
    __syncthreads();

    bf16x8 a2[4];
    #pragma unroll
    for (int kk = 0; kk < 4; ++kk) {
        int byte = (arow * 256 + kk * 64 + (lane >> 4) * 16) ^ ((arow & 7) << 4);
        a2[kk] = *(const bf16x8*)((const char*)As + byte);
    }
    f32x4 acc2[8];
    #pragma unroll
    for (int nt = 0; nt < 8; ++nt) acc2[nt] = zero;
    const bf16x8* W3p8 = (const bf16x8*)W3p;
    #pragma unroll
    for (int nt = 0; nt < 8; ++nt)
        #pragma unroll
        for (int kk = 0; kk < 4; ++kk)
            acc2[nt] = __builtin_amdgcn_mfma_f32_16x16x32_bf16(
                a2[kk], W3p8[(nt * 4 + kk) * 64 + lane], acc2[nt], 0, 0, 0);

    bool last = (OW1p != nullptr);
    // h_new = h_old + acc2 + b3: write global (except last iter, where h is
    // dead) and write bf16 into own LDS stripe for the third GEMM pass.
    #pragma unroll
    for (int nt = 0; nt < 8; ++nt) {
        int col = nt * 16 + (lane & 15);
        float bv3 = b3[col];
        #pragma unroll
        for (int r = 0; r < 4; ++r) {
            int lrow = w * 16 + (lane >> 4) * 4 + r;
            int row = base + lrow;
            float hv = 0.f;
            if (row < nrows) hv = h[(size_t)row * 128 + col];
            float nv = hv + acc2[nt][r] + bv3;
            if (!last && row < nrows) h[(size_t)row * 128 + col] = nv;
            int byte = (lrow * 256 + col * 2) ^ ((lrow & 7) << 4);
            *(unsigned short*)((char*)As + byte) = f2bf(nv);
        }
    }
    __syncthreads();

    bf16x8 a3[4];
    #pragma unroll
    for (int kk = 0; kk < 4; ++kk) {
        int byte = (arow * 256 + kk * 64 + (lane >> 4) * 16) ^ ((arow & 7) << 4);
        a3[kk] = *(const bf16x8*)((const char*)As + byte);
    }

    if (!last) {
        // x_next = h_new @ Wnext -> xb (bf16)
        f32x4 acc3[8];
        #pragma unroll
        for (int nt = 0; nt < 8; ++nt) acc3[nt] = zero;
        const bf16x8* Wn8 = (const bf16x8*)Wnext;
        #pragma unroll
        for (int nt = 0; nt < 8; ++nt)
            #pragma unroll
            for (int kk = 0; kk < 4; ++kk)
                acc3[nt] = __builtin_amdgcn_mfma_f32_16x16x32_bf16(
                    a3[kk], Wn8[(nt * 4 + kk) * 64 + lane], acc3[nt], 0, 0, 0);
        #pragma unroll
        for (int nt = 0; nt < 8; ++nt) {
            int col = nt * 16 + (lane & 15);
            #pragma unroll
            for (int r = 0; r < 4; ++r) {
                int row = base + w * 16 + (lane >> 4) * 4 + r;
                if (row < nrows) xb[(size_t)row * 128 + col] = f2bf(acc3[nt][r]);
            }
        }
    } else {
        // readout: p = ssp(h_new @ OW1 + ob1) . ow2, segment-sum by batch
        f32x4 acc4[4];
        #pragma unroll
        for (int nt = 0; nt < 4; ++nt) acc4[nt] = zero;
        const bf16x8* W8 = (const bf16x8*)OW1p;
        #pragma unroll
        for (int nt = 0; nt < 4; ++nt)
            #pragma unroll
            for (int kk = 0; kk < 4; ++kk)
                acc4[nt] = __builtin_amdgcn_mfma_f32_16x16x32_bf16(
                    a3[kk], W8[(nt * 4 + kk) * 64 + lane], acc4[nt], 0, 0, 0);
        float p[4] = {0.f, 0.f, 0.f, 0.f};
        #pragma unroll
        for (int nt = 0; nt < 4; ++nt) {
            int col = nt * 16 + (lane & 15);
            float b = ob1[col], wv = ow2[col];
            #pragma unroll
            for (int r = 0; r < 4; ++r) p[r] += ssp(acc4[nt][r] + b) * wv;
        }
        #pragma unroll
        for (int m = 1; m < 16; m <<= 1) {
            #pragma unroll
            for (int r = 0; r < 4; ++r) p[r] += __shfl_xor(p[r], m);
        }
        if ((lane & 15) == 0) {
            #pragma unroll
            for (int r = 0; r < 4; ++r) rowsum[w * 16 + (lane >> 4) * 4 + r] = p[r];
        }
        __syncthreads();
        if (tid < 64) {
            int row = base + tid;
            int rc = row < nrows ? row : nrows - 1;
            int g = batch[rc];
            float v = (row < nrows) ? rowsum[tid] + ob2[0] : 0.f;
            #pragma unroll
            for (int off = 1; off < 64; off <<= 1) {
                float vo = __shfl_down(v, off);
                int   go = __shfl_down(g, off);
                if (tid + off < 64 && go == g) v += vo;
            }
            int gp = __shfl_up(g, 1);
            if (row < nrows && (tid == 0 || gp != g))
                unsafeAtomicAdd(&energy[g], v);
        }
    }
}

// ---------------- aggregation: 1 wave/node, unroll x4, paired T --------------
__device__ __forceinline__ void lerp_acc(unsigned int ta, unsigned int tb,
                                         unsigned int xv, float fr, float2& acc) {
    float t0a = bf2f(ta & 0xffffu), t0b = bf2f(ta >> 16);
    float t1a = bf2f(tb & 0xffffu), t1b = bf2f(tb >> 16);
    acc.x = fmaf(bf2f(xv & 0xffffu), fmaf(t1a - t0a, fr, t0a), acc.x);
    acc.y = fmaf(bf2f(xv >> 16),     fmaf(t1b - t0b, fr, t0b), acc.y);
}

__global__ __launch_bounds__(256) void k_agg(
        const int* __restrict__ offs, const int2* __restrict__ payload,
        const unsigned int* __restrict__ xw, const uint2* __restrict__ Tp,
        unsigned int* __restrict__ aggp) {
    int wid = threadIdx.x >> 6, lane = threadIdx.x & 63;
    int n = blockIdx.x * 4 + wid;
    int beg = offs[n], end = offs[n + 1];
    float2 acc = make_float2(0.f, 0.f);
    int e = beg, cnt = end - beg;
    int2 p0, p1, p2, p3;
    if (cnt >= 4) { p0 = payload[e]; p1 = payload[e + 1]; p2 = payload[e + 2]; p3 = payload[e + 3]; }
    while (cnt >= 4) {
        unsigned int c0 = p0.x, c1 = p1.x, c2 = p2.x, c3 = p3.x;
        float u0 = __int_as_float(p0.y), u1 = __int_as_float(p1.y);
        float u2 = __int_as_float(p2.y), u3 = __int_as_float(p3.y);
        int j0 = (int)u0, j1 = (int)u1, j2 = (int)u2, j3 = (int)u3;
        float f0 = u0 - j0, f1 = u1 - j1, f2 = u2 - j2, f3 = u3 - j3;
        // issue all 8 gathers before any FMA
        uint2 t0 = Tp[(size_t)j0 * 64 + lane];
        uint2 t1 = Tp[(size_t)j1 * 64 + lane];
        uint2 t2 = Tp[(size_t)j2 * 64 + lane];
        uint2 t3 = Tp[(size_t)j3 * 64 + lane];
        unsigned int xv0 = xw[(size_t)c0 * 64 + lane];
        unsigned int xv1 = xw[(size_t)c1 * 64 + lane];
        unsigned int xv2 = xw[(size_t)c2 * 64 + lane];
        unsigned int xv3 = xw[(size_t)c3 * 64 + lane];
        e += 4; cnt -= 4;
        if (cnt >= 4) { p0 = payload[e]; p1 = payload[e + 1]; p2 = payload[e + 2]; p3 = payload[e + 3]; }
        lerp_acc(t0.x, t0.y, xv0, f0, acc);
        lerp_acc(t1.x, t1.y, xv1, f1, acc);
        lerp_acc(t2.x, t2.y, xv2, f2, acc);
        lerp_acc(t3.x, t3.y, xv3, f3, acc);
    }
    for (; cnt > 0; --cnt, ++e) {
        int2 cur = payload[e];
        float u = __int_as_float(cur.y);
        int j = (int)u;
        float fr = u - (float)j;
        uint2 t = Tp[(size_t)j * 64 + lane];
        unsigned int xv = xw[(size_t)cur.x * 64 + lane];
        lerp_acc(t.x, t.y, xv, fr, acc);
    }
    // store bf16 pair at the PRE-SWIZZLED position (16B-chunk XOR permutation)
    unsigned int ov = (unsigned int)f2bf(acc.x) | ((unsigned int)f2bf(acc.y) << 16);
    aggp[(size_t)n * 64 + (((lane >> 2) ^ (n & 7)) << 2) + (lane & 3)] = ov;
}

extern "C" void kernel_launch(void* const* d_in, const int* in_sizes, int n_in,
                              void* d_out, int out_size, void* d_ws, size_t ws_size,
                              hipStream_t stream) {
    const float* pos    = (const float*)d_in[0];
    const float* emb    = (const float*)d_in[1];
    const float* w1     = (const float*)d_in[2];
    const float* b1     = (const float*)d_in[3];
    const float* w2     = (const float*)d_in[4];
    const float* b2     = (const float*)d_in[5];
    const float* lin1_w = (const float*)d_in[6];
    const float* lin2_w = (const float*)d_in[7];
    const float* lin2_b = (const float*)d_in[8];
    const float* lin_w  = (const float*)d_in[9];
    const float* lin_b  = (const float*)d_in[10];
    const float* ow1    = (const float*)d_in[11];
    const float* ob1    = (const float*)d_in[12];
    const float* ow2    = (const float*)d_in[13];
    const float* ob2    = (const float*)d_in[14];
    const int*   z      = (const int*)d_in[15];
    const int*   batch  = (const int*)d_in[16];
    const int*   ei     = (const int*)d_in[17];
    float* energy = (float*)d_out;

    char* ws = (char*)d_ws;
    float*          h       = (float*)ws;          ws += (size_t)Nn * 128 * 4;
    unsigned int*   aggp    = (unsigned int*)ws;   ws += (size_t)Nn * 128 * 2;
    unsigned short* xb      = (unsigned short*)ws; ws += (size_t)Nn * 128 * 2;
    unsigned short* T       = (unsigned short*)ws; ws += (size_t)TS * 128 * 2;
    uint2*          Tp      = (uint2*)ws;          ws += (size_t)TS * 64 * 8;
    int2*           payload = (int2*)ws;           ws += (size_t)Ee * 8;
    short*          Wp      = (short*)ws;          ws += ((size_t)18 * 16384 + 8192) * 2;
    int*            counts  = (int*)ws;            ws += (size_t)Nn * 4;
    int*            offsets = (int*)ws;            ws += (size_t)(Nn + 1) * 4;
    int*            cursor  = (int*)ws;            ws += (size_t)Nn * 4;
    int*            incl    = (int*)ws;            ws += (size_t)Nn * 4;
    int*            bsum    = (int*)ws;            ws += (size_t)256 * 4;

    float step = DMAXv / (TS - 1);
    float inv_step = (TS - 1) / DMAXv;

    hipMemsetAsync(d_out, 0, Gg * 4, stream);
    hipMemsetAsync(counts, 0, (size_t)Nn * 4, stream);
    k_embed<<<Nn * 128 / 256, 256, 0, stream>>>(emb, z, h);

    // CSR sort of edges by target row (parallel 3-phase scan)
    k_hist<<<(Ee + 255) / 256, 256, 0, stream>>>(ei, counts);
    k_scanA<<<NB, 256, 0, stream>>>(counts, incl, bsum);
    k_scanB<<<1, 256, 0, stream>>>(bsum);
    k_scanC<<<NB, 256, 0, stream>>>(counts, incl, bsum, offsets, cursor);
    k_scatter<<<(Ee + 255) / 256, 256, 0, stream>>>(ei, pos, cursor, payload, inv_step);

    // pack 18 interaction matrices + ow1 to MFMA fragment layout (bf16)
    k_pack<<<(18 * 16384 + 8192) / 256, 256, 0, stream>>>(lin1_w, lin2_w, lin_w, ow1, Wp);

    int gemm_blocks = (Nn + 63) / 64;
    const short* OWp = Wp + (size_t)18 * 16384;

    k_table<<<512, 256, 0, stream>>>(w1, b1, w2, b2, T, step);
    k_pair<<<TS * 64 / 256, 256, 0, stream>>>((const unsigned int*)T, Tp);
    k_mfma1<<<gemm_blocks, 256, 0, stream>>>(h, Wp, xb, Nn);

    for (int i = 0; i < NIi; ++i) {
        const short* W2p = Wp + (size_t)(i * 3 + 1) * 16384;
        const short* W3p = Wp + (size_t)(i * 3 + 2) * 16384;
        bool last = (i == NIi - 1);
        const short* Wnext = last ? nullptr : Wp + (size_t)((i + 1) * 3) * 16384;

        k_agg<<<Nn / 4, 256, 0, stream>>>(offsets, payload,
                                          (const unsigned int*)xb, Tp, aggp);
        if (!last) {
            k_table<<<512, 256, 0, stream>>>(w1 + (size_t)(i + 1) * NGg * 128,
                                             b1 + (size_t)(i + 1) * 128,
                                             w2 + (size_t)(i + 1) * 128 * 128,
                                             b2 + (size_t)(i + 1) * 128, T, step);
            k_pair<<<TS * 64 / 256, 256, 0, stream>>>((const unsigned int*)T, Tp);
        }
        k_fused<<<gemm_blocks, 256, 0, stream>>>(
            aggp, W2p, lin2_b + (size_t)i * Hh, W3p, lin_b + (size_t)i * Hh, h,
            Wnext, xb, last ? OWp : nullptr, ob1, ow2, ob2, batch, energy, Nn);
    }
}